// Round 9
// baseline (572.278 us; speedup 1.0000x reference)
//
#include <hip/hip_runtime.h>
#include <hip/hip_fp16.h>
#include <math.h>

#define NN 100000
#define EE 1600000
#define DD 128
#define NBUCK 196          // ceil(NN / 512) buckets of 512 dst nodes
#define NBLKP 196          // partition blocks, 8192 edges each (196*8192 >= EE)
#define EPB 8192           // edges per partition block

typedef _Float16 f16;
typedef f16 f16x8 __attribute__((ext_vector_type(8)));
typedef float f32x4 __attribute__((ext_vector_type(4)));
typedef int int32x4 __attribute__((ext_vector_type(4)));

// raw buffer load bound directly to the LLVM intrinsic (CK pattern): compiler
// tracks the dependency and inserts waitcnts itself (no inline-asm hazard).
__device__ float llvm_amdgcn_raw_buffer_load_fp32(int32x4 srsrc, int voffset, int soffset,
                                                  int aux) __asm("llvm.amdgcn.raw.buffer.load.f32");

#define LDA 136            // padded LDS row stride in halves (272 B = 17*16)
#define WCHUNKS 2304       // 36864 B per W matrix image (128*136 halves + pad)

// ---------- bucketed CSR build ----------
__global__ __launch_bounds__(256) void part_hist_k(const int* __restrict__ dst, int* __restrict__ bcnt) {
    __shared__ int lc[NBUCK];
    int t = threadIdx.x, blk = blockIdx.x;
    if (t < NBUCK) lc[t] = 0;
    __syncthreads();
    int e0 = blk * EPB;
    for (int i = t; i < EPB; i += 256) {
        int e = e0 + i;
        if (e < EE) atomicAdd(&lc[dst[e] >> 9], 1);
    }
    __syncthreads();
    if (t < NBUCK) bcnt[t * NBLKP + blk] = lc[t];
}

__global__ __launch_bounds__(256) void scanBB_k(const int* __restrict__ bcnt, int* __restrict__ ebase,
                                                int* __restrict__ btot) {
    __shared__ int sh[256];
    int t = threadIdx.x, b = blockIdx.x;
    int c = (t < NBLKP) ? bcnt[b * NBLKP + t] : 0;
    sh[t] = c;
    __syncthreads();
    for (int off = 1; off < 256; off <<= 1) {
        int v = (t >= off) ? sh[t - off] : 0;
        __syncthreads();
        sh[t] += v;
        __syncthreads();
    }
    if (t < NBLKP) ebase[b * NBLKP + t] = sh[t] - c;  // exclusive
    if (t == 255) btot[b] = sh[255];
}

__global__ __launch_bounds__(256) void scanBT_k(const int* __restrict__ btot, int* __restrict__ bstart,
                                                int* __restrict__ offsets) {
    __shared__ int sh[256];
    int t = threadIdx.x;
    int c = (t < NBUCK) ? btot[t] : 0;
    sh[t] = c;
    __syncthreads();
    for (int off = 1; off < 256; off <<= 1) {
        int v = (t >= off) ? sh[t - off] : 0;
        __syncthreads();
        sh[t] += v;
        __syncthreads();
    }
    if (t < NBUCK) bstart[t] = sh[t] - c;
    if (t == 0) { bstart[NBUCK] = EE; offsets[NN] = EE; }
}

__global__ __launch_bounds__(256) void part_k(const int* __restrict__ src, const int* __restrict__ dst,
                                              const int* __restrict__ bstart, const int* __restrict__ ebase,
                                              int2* __restrict__ ebuf) {
    __shared__ int cur[NBUCK];
    int t = threadIdx.x, blk = blockIdx.x;
    if (t < NBUCK) cur[t] = bstart[t] + ebase[t * NBLKP + blk];
    __syncthreads();
    int e0 = blk * EPB;
    for (int i = t; i < EPB; i += 256) {
        int e = e0 + i;
        if (e < EE) {
            int s = src[e], d = dst[e];
            int p = atomicAdd(&cur[d >> 9], 1);
            ebuf[p] = make_int2(s, d);
        }
    }
}

__global__ __launch_bounds__(512) void bucket_sort_k(const int2* __restrict__ ebuf,
                                                     const int* __restrict__ bstart,
                                                     int* __restrict__ offsets,
                                                     int* __restrict__ ssrc) {
    __shared__ int sh[512];
    __shared__ int cur[512];
    int t = threadIdx.x, b = blockIdx.x;
    int d0 = b << 9;
    int beg = bstart[b], end = bstart[b + 1];

    if (b == 0 && t < 16) ssrc[EE + t] = 0;   // pad records (weights masked in agg)

    cur[t] = 0;
    __syncthreads();
    for (int e = beg + t; e < end; e += 512) atomicAdd(&cur[ebuf[e].y - d0], 1);
    __syncthreads();
    int c = cur[t];
    sh[t] = c;
    __syncthreads();
    for (int off = 1; off < 512; off <<= 1) {
        int v = (t >= off) ? sh[t - off] : 0;
        __syncthreads();
        sh[t] += v;
        __syncthreads();
    }
    int excl = sh[t] - c;
    if (d0 + t < NN) offsets[d0 + t] = beg + excl;
    cur[t] = beg + excl;
    __syncthreads();
    for (int e = beg + t; e < end; e += 512) {
        int2 ed = ebuf[e];
        int p = atomicAdd(&cur[ed.y - d0], 1);
        ssrc[p] = ed.x;
    }
}

// ---------------- W prep: transpose + fp16 round into LDS-image layout; wa = W @ a ----------------
__global__ __launch_bounds__(256) void wprep_k(const float* __restrict__ W_in,
                                               const float* __restrict__ Wl,
                                               const float* __restrict__ att_src,
                                               const float* __restrict__ att_dst,
                                               f16* __restrict__ Wt,
                                               float* __restrict__ wav) {
    int m = blockIdx.x;  // 0..4
    const float* src = (m == 0) ? W_in : (Wl + (size_t)(m - 1) * DD * DD);
    f16* dst = Wt + (size_t)m * (WCHUNKS * 8);
    for (int q = 0; q < 64; ++q) {
        int idx = q * 256 + threadIdx.x;   // 0..16383  (= k*128 + n)
        int k = idx >> 7, n = idx & 127;
        dst[n * LDA + k] = (f16)src[idx];
    }
    if (m >= 1) {
        // wa[k] = sum_n W[k][n] * a[n]  (exact f32; alpha = h . wa == (h@W) . a)
        int t = threadIdx.x;
        const float* av = (t < 128) ? (att_src + (size_t)(m - 1) * DD)
                                    : (att_dst + (size_t)(m - 1) * DD);
        int k = t & 127;
        float s = 0.f;
        for (int n = 0; n < 128; ++n) s += src[k * 128 + n] * av[n];
        wav[(size_t)(m - 1) * 256 + (t >> 7) * 128 + k] = s;
    }
}

// ---------------- GEMM: tmp = h @ W via fp16 MFMA + input-side alpha dots ----------------
// (R6-measured form: 2 blocks/CU, separate sOut buffer.)
template <int FUSED>
__global__ __launch_bounds__(256, 2) void gemm_k(const void* __restrict__ Xv,
                                                 const f16* __restrict__ Wt0,
                                                 const f16* __restrict__ Wt1,
                                                 const float* __restrict__ bias,
                                                 const float* __restrict__ wa_s,
                                                 const float* __restrict__ wa_d,
                                                 __half* __restrict__ Yh,
                                                 float* __restrict__ alpha_src,
                                                 float* __restrict__ alpha_dst) {
    __shared__ __align__(16) f16 sW[WCHUNKS * 8];      // 36864 B
    __shared__ __align__(16) f16 sOut[4][32][LDA];     // 34816 B, padded rows (bank-safe)
    int t = threadIdx.x;
    int w = t >> 6, lane = t & 63;
    int cl = lane & 15, qw = lane >> 4;
    int row0 = blockIdx.x * 128;

    // A fragments: row = row0 + w*32 + rf*16 + cl, k-span = ks*32 + qw*8 .. +8
    f16x8 a[2][4];
    if (FUSED) {
        const float* X = (const float*)Xv;
#pragma unroll
        for (int rf = 0; rf < 2; ++rf) {
            int row = row0 + w * 32 + rf * 16 + cl;
            row = row < NN ? row : NN - 1;      // clamp (guarded at write)
            const float* p = X + (size_t)row * DD;
#pragma unroll
            for (int ks = 0; ks < 4; ++ks) {
                float4 u0 = *(const float4*)(p + ks * 32 + qw * 8);
                float4 u1 = *(const float4*)(p + ks * 32 + qw * 8 + 4);
                f16x8 v;
                v[0] = (f16)u0.x; v[1] = (f16)u0.y; v[2] = (f16)u0.z; v[3] = (f16)u0.w;
                v[4] = (f16)u1.x; v[5] = (f16)u1.y; v[6] = (f16)u1.z; v[7] = (f16)u1.w;
                a[rf][ks] = v;
            }
        }
    } else {
        const f16* X = (const f16*)Xv;
#pragma unroll
        for (int rf = 0; rf < 2; ++rf) {
            int row = row0 + w * 32 + rf * 16 + cl;
            row = row < NN ? row : NN - 1;
            const f16* p = X + (size_t)row * DD;
#pragma unroll
            for (int ks = 0; ks < 4; ++ks)
                a[rf][ks] = *(const f16x8*)(p + ks * 32 + qw * 8);
        }
    }

    // stage W image
    {
        const uint4* wsrc = (const uint4*)Wt0;
        uint4* wdst = (uint4*)sW;
#pragma unroll
        for (int it = 0; it < 9; ++it) wdst[it * 256 + t] = wsrc[it * 256 + t];
    }
    __syncthreads();

    f32x4 acc[2][8] = {};
#pragma unroll
    for (int ks = 0; ks < 4; ++ks) {
        int koff = ks * 32 + qw * 8;
#pragma unroll
        for (int nf = 0; nf < 8; ++nf) {
            f16x8 bh = *(const f16x8*)(sW + (nf * 16 + cl) * LDA + koff);
            acc[0][nf] = __builtin_amdgcn_mfma_f32_16x16x32_f16(a[0][ks], bh, acc[0][nf], 0, 0, 0);
            acc[1][nf] = __builtin_amdgcn_mfma_f32_16x16x32_f16(a[1][ks], bh, acc[1][nf], 0, 0, 0);
        }
    }

    if (FUSED) {
        __syncthreads();   // all waves done reading W_in image
        // restage W with Wl_0 image
        {
            const uint4* wsrc = (const uint4*)Wt1;
            uint4* wdst = (uint4*)sW;
#pragma unroll
            for (int it = 0; it < 9; ++it) wdst[it * 256 + t] = wsrc[it * 256 + t];
        }
        // h0 = leaky(acc + bias) -> own wave's sOut region (fp16)
        float bc[8];
#pragma unroll
        for (int nf = 0; nf < 8; ++nf) bc[nf] = bias[nf * 16 + cl];
#pragma unroll
        for (int rf = 0; rf < 2; ++rf)
#pragma unroll
            for (int i = 0; i < 4; ++i)
#pragma unroll
                for (int nf = 0; nf < 8; ++nf) {
                    float v = acc[rf][nf][i] + bc[nf];
                    v = v > 0.f ? v : 0.01f * v;
                    sOut[w][rf * 16 + qw * 4 + i][nf * 16 + cl] = (f16)v;
                }
        __syncthreads();   // Wl_0 image staged
        // reload A fragments from h0 tile (within-wave LDS dependency)
#pragma unroll
        for (int rf = 0; rf < 2; ++rf)
#pragma unroll
            for (int ks = 0; ks < 4; ++ks)
                a[rf][ks] = *(const f16x8*)&sOut[w][rf * 16 + cl][ks * 32 + qw * 8];
        // second MFMA chain: tmp = h0 @ Wl_0
#pragma unroll
        for (int rf = 0; rf < 2; ++rf)
#pragma unroll
            for (int nf = 0; nf < 8; ++nf)
                acc[rf][nf] = (f32x4){0.f, 0.f, 0.f, 0.f};
#pragma unroll
        for (int ks = 0; ks < 4; ++ks) {
            int koff = ks * 32 + qw * 8;
#pragma unroll
            for (int nf = 0; nf < 8; ++nf) {
                f16x8 bh = *(const f16x8*)(sW + (nf * 16 + cl) * LDA + koff);
                acc[0][nf] = __builtin_amdgcn_mfma_f32_16x16x32_f16(a[0][ks], bh, acc[0][nf], 0, 0, 0);
                acc[1][nf] = __builtin_amdgcn_mfma_f32_16x16x32_f16(a[1][ks], bh, acc[1][nf], 0, 0, 0);
            }
        }
    }

    // ---- alpha dots from input-side fragments: alpha = h . wa ----
#pragma unroll
    for (int rf = 0; rf < 2; ++rf) {
        float pa = 0.f, pb = 0.f;
#pragma unroll
        for (int ks = 0; ks < 4; ++ks) {
            const float* ps = wa_s + ks * 32 + qw * 8;
            const float* pd = wa_d + ks * 32 + qw * 8;
            float4 s0 = *(const float4*)ps, s1 = *(const float4*)(ps + 4);
            float4 d0 = *(const float4*)pd, d1 = *(const float4*)(pd + 4);
            float sv[8] = {s0.x, s0.y, s0.z, s0.w, s1.x, s1.y, s1.z, s1.w};
            float dv[8] = {d0.x, d0.y, d0.z, d0.w, d1.x, d1.y, d1.z, d1.w};
#pragma unroll
            for (int e = 0; e < 8; ++e) {
                float f = (float)a[rf][ks][e];
                pa = fmaf(f, sv[e], pa);
                pb = fmaf(f, dv[e], pb);
            }
        }
        pa += __shfl_xor(pa, 16); pa += __shfl_xor(pa, 32);
        pb += __shfl_xor(pb, 16); pb += __shfl_xor(pb, 32);
        if (qw == 0) {
            int row = row0 + w * 32 + rf * 16 + cl;
            if (row < NN) {
                alpha_src[row] = pa;
                alpha_dst[row] = pb;
            }
        }
    }

    // ---- tmp store via LDS transpose (coalesced 16 B stores) ----
#pragma unroll
    for (int rf = 0; rf < 2; ++rf)
#pragma unroll
        for (int i = 0; i < 4; ++i)
#pragma unroll
            for (int nf = 0; nf < 8; ++nf)
                sOut[w][rf * 16 + qw * 4 + i][nf * 16 + cl] = (f16)acc[rf][nf][i];
#pragma unroll
    for (int p = 0; p < 8; ++p) {
        int rl = p * 4 + qw;
        uint4 v = *(const uint4*)&sOut[w][rl][cl * 8];
        int row = row0 + w * 32 + rl;
        if (row < NN) *(uint4*)(Yh + (size_t)row * DD + cl * 8) = v;
    }
}

// ---------------- Per-dst aggregation (edge weights computed in-kernel) ----------------
// one wave per dst node; lane c owns channels 2c, 2c+1. ssrc read via uniform
// s_load_dwordx4 (4 edges per load); alpha_src[s] via uniform scalar loads (L2-hot
// 400 KB array); weight = exp(leaky(a_s + a_d)) on wave-uniform VALU; gathers via
// SRSRC buffer_load with SGPR soffset.
template <int HOUT>
__global__ __launch_bounds__(256) void agg_k(const __half* __restrict__ tmp,
                                             const int* __restrict__ ssrc,
                                             const int* __restrict__ offsets,
                                             const float* __restrict__ alpha_src,
                                             const float* __restrict__ alpha_dst,
                                             const float* __restrict__ bias,
                                             const float* __restrict__ gamma,
                                             const float* __restrict__ beta,
                                             void* __restrict__ outv) {
    int wid = (blockIdx.x * 256 + threadIdx.x) >> 6;
    wid = __builtin_amdgcn_readfirstlane(wid);
    int lane = threadIdx.x & 63;
    int beg = __builtin_amdgcn_readfirstlane(offsets[wid]);
    int end = __builtin_amdgcn_readfirstlane(offsets[wid + 1]);
    float adst = alpha_dst[wid];

    int32x4 rsrc;
    {
        unsigned long long b = (unsigned long long)(uintptr_t)tmp;
        rsrc.x = (int)(b & 0xffffffffull);
        rsrc.y = (int)(b >> 32);
        rsrc.z = NN * 256;          // num_records in bytes
        rsrc.w = 0x00020000;        // raw dword access
    }
    int voff = lane << 2;

    float ax0 = 0.f, ay0 = 0.f, ax1 = 0.f, ay1 = 0.f, dsum = 0.f;

    for (int j = (beg & ~3); j < end; j += 16) {
        int4 sq[4];
#pragma unroll
        for (int k = 0; k < 4; ++k) sq[k] = *(const int4*)(ssrc + j + 4 * k);
        int sv[16];
#pragma unroll
        for (int k = 0; k < 4; ++k) {
            sv[4 * k] = sq[k].x; sv[4 * k + 1] = sq[k].y;
            sv[4 * k + 2] = sq[k].z; sv[4 * k + 3] = sq[k].w;
        }
        // issue all 16 gathers first (scalar soffset), weights compute under their latency
        float g[16];
#pragma unroll
        for (int k = 0; k < 16; ++k)
            g[k] = llvm_amdgcn_raw_buffer_load_fp32(rsrc, voff, sv[k] << 8, 0);
        float w[16];
#pragma unroll
        for (int k = 0; k < 16; ++k) {
            float e = alpha_src[sv[k]] + adst;
            e = e > 0.f ? e : 0.2f * e;
            float ww = __expf(e);
            int ei = j + k;
            w[k] = (ei >= beg && ei < end) ? ww : 0.f;
            dsum += w[k];
        }
#pragma unroll
        for (int k = 0; k < 16; ++k) {
            union { float f; __half2 h; } u;
            u.f = g[k];
            if (k & 1) {
                ax1 = fmaf(w[k], __half2float(u.h.x), ax1);
                ay1 = fmaf(w[k], __half2float(u.h.y), ay1);
            } else {
                ax0 = fmaf(w[k], __half2float(u.h.x), ax0);
                ay0 = fmaf(w[k], __half2float(u.h.y), ay0);
            }
        }
    }

    // dsum is lane-uniform: no cross-lane reduction needed
    float inv = 1.0f / (dsum + 1e-16f);

    float ax = (ax0 + ax1) * inv + bias[2 * lane];
    float ay = (ay0 + ay1) * inv + bias[2 * lane + 1];

    float s1 = ax + ay;
#pragma unroll
    for (int off = 32; off >= 1; off >>= 1) s1 += __shfl_xor(s1, off);
    float mu = s1 * (1.0f / 128.0f);
    float dx = ax - mu, dy = ay - mu;
    float s2 = dx * dx + dy * dy;
#pragma unroll
    for (int off = 32; off >= 1; off >>= 1) s2 += __shfl_xor(s2, off);
    float rstd = rsqrtf(s2 * (1.0f / 128.0f) + 1e-5f);

    float yx = dx * rstd * gamma[2 * lane] + beta[2 * lane];
    float yy = dy * rstd * gamma[2 * lane + 1] + beta[2 * lane + 1];
    yx = yx > 0.f ? yx : 0.01f * yx;
    yy = yy > 0.f ? yy : 0.01f * yy;
    if (HOUT) {
        ((__half2*)outv)[(size_t)wid * 64 + lane] = __floats2half2_rn(yx, yy);
    } else {
        ((float2*)outv)[(size_t)wid * 64 + lane] = make_float2(yx, yy);
    }
}

extern "C" void kernel_launch(void* const* d_in, const int* in_sizes, int n_in,
                              void* d_out, int out_size, void* d_ws, size_t ws_size,
                              hipStream_t stream) {
    const float* x       = (const float*)d_in[0];
    const int*   ei      = (const int*)d_in[1];
    const float* W_in    = (const float*)d_in[2];
    const float* b_in    = (const float*)d_in[3];
    const float* Wl      = (const float*)d_in[4];
    const float* att_src = (const float*)d_in[5];
    const float* att_dst = (const float*)d_in[6];
    const float* bias_l  = (const float*)d_in[7];
    const float* gamma   = (const float*)d_in[8];
    const float* beta    = (const float*)d_in[9];
    float* out = (float*)d_out;

    char* ws = (char*)d_ws;
    __half* tmp      = (__half*)ws; ws += (size_t)NN * DD * 2;   // 25.6 MB
    float* alpha_src = (float*)ws;  ws += (size_t)NN * 4;
    float* alpha_dst = (float*)ws;  ws += (size_t)NN * 4;
    int*   offsets   = (int*)ws;    ws += (size_t)(NN + 4) * 4;
    int*   ssrc      = (int*)ws;    ws += (size_t)(EE + 16) * 4; // 6.4 MB (+pad)
    int2*  ebuf      = (int2*)ws;   ws += (size_t)EE * 8;        // 12.8 MB (dead after CSR build)
    int*   bcnt      = (int*)ws;    ws += (size_t)NBUCK * NBLKP * 4;
    int*   ebase     = (int*)ws;    ws += (size_t)NBUCK * NBLKP * 4;
    int*   btot      = (int*)ws;    ws += (size_t)(NBUCK + 4) * 4;
    int*   bstart    = (int*)ws;    ws += (size_t)(NBUCK + 4) * 4;
    f16*   Wt        = (f16*)ws;    ws += (size_t)5 * WCHUNKS * 16;  // 184 KB
    float* wav       = (float*)ws;  ws += (size_t)4 * 256 * 4;       // 4 KB (wa vectors)

    // fp16 hidden-state buffer lives in the (not-yet-needed) d_out allocation:
    // layers 0..2 store h as fp16 in the first 25.6 MB; the final agg_k fully
    // overwrites d_out with fp32 output.
    __half* hbuf = (__half*)d_out;

    const int* esrc = ei;
    const int* edst = ei + EE;

    // bucketed CSR build (edges constant within a launch)
    part_hist_k<<<NBLKP, 256, 0, stream>>>(edst, bcnt);
    scanBB_k<<<NBUCK, 256, 0, stream>>>(bcnt, ebase, btot);
    scanBT_k<<<1, 256, 0, stream>>>(btot, bstart, offsets);
    part_k<<<NBLKP, 256, 0, stream>>>(esrc, edst, bstart, ebase, ebuf);
    bucket_sort_k<<<NBUCK, 512, 0, stream>>>(ebuf, bstart, offsets, ssrc);
    wprep_k<<<5, 256, 0, stream>>>(W_in, Wl, att_src, att_dst, Wt, wav);

    const int gg = (NN + 127) / 128;          // 782

    // layer 0: fused  tmp = (leaky(x@W_in + b)) @ Wl_0  + alpha_0  (h0 never hits HBM)
    gemm_k<1><<<gg, 256, 0, stream>>>(x, Wt, Wt + (size_t)1 * (WCHUNKS * 8), b_in,
                                      wav, wav + 128, tmp, alpha_src, alpha_dst);
    agg_k<1><<<NN / 4, 256, 0, stream>>>(tmp, ssrc, offsets, alpha_src, alpha_dst,
                                         bias_l, gamma, beta, (void*)hbuf);

    for (int i = 1; i < 4; i++) {
        gemm_k<0><<<gg, 256, 0, stream>>>(hbuf, Wt + (size_t)(i + 1) * (WCHUNKS * 8), nullptr, nullptr,
                                          wav + (size_t)i * 256, wav + (size_t)i * 256 + 128,
                                          tmp, alpha_src, alpha_dst);
        if (i < 3) {
            agg_k<1><<<NN / 4, 256, 0, stream>>>(tmp, ssrc, offsets, alpha_src, alpha_dst,
                                                 bias_l + (size_t)i * DD, gamma + (size_t)i * DD,
                                                 beta + (size_t)i * DD, (void*)hbuf);
        } else {
            agg_k<0><<<NN / 4, 256, 0, stream>>>(tmp, ssrc, offsets, alpha_src, alpha_dst,
                                                 bias_l + (size_t)i * DD, gamma + (size_t)i * DD,
                                                 beta + (size_t)i * DD, (void*)out);
        }
    }
}

// Round 10
// 545.328 us; speedup vs baseline: 1.0494x; 1.0494x over previous
//
#include <hip/hip_runtime.h>
#include <hip/hip_fp16.h>
#include <math.h>

#define NN 100000
#define EE 1600000
#define DD 128
#define NBUCK 196          // ceil(NN / 512) buckets of 512 dst nodes
#define NBLKP 196          // partition blocks, 8192 edges each (196*8192 >= EE)
#define EPB 8192           // edges per partition block

typedef _Float16 f16;
typedef f16 f16x8 __attribute__((ext_vector_type(8)));
typedef float f32x4 __attribute__((ext_vector_type(4)));
typedef int int32x4 __attribute__((ext_vector_type(4)));

// raw buffer load bound directly to the LLVM intrinsic (CK pattern): compiler
// tracks the dependency and inserts waitcnts itself (no inline-asm hazard).
__device__ float llvm_amdgcn_raw_buffer_load_fp32(int32x4 srsrc, int voffset, int soffset,
                                                  int aux) __asm("llvm.amdgcn.raw.buffer.load.f32");

#define LDA 136            // padded LDS row stride in halves (272 B = 17*16)
#define WCHUNKS 2304       // 36864 B per W matrix image slot (layout stride)
#define WCOPY 2176         // 34816 B actually used by a 128x(LDA) image

// ---------- bucketed CSR build ----------
__global__ __launch_bounds__(256) void part_hist_k(const int* __restrict__ dst, int* __restrict__ bcnt) {
    __shared__ int lc[NBUCK];
    int t = threadIdx.x, blk = blockIdx.x;
    if (t < NBUCK) lc[t] = 0;
    __syncthreads();
    int e0 = blk * EPB;
    for (int i = t; i < EPB; i += 256) {
        int e = e0 + i;
        if (e < EE) atomicAdd(&lc[dst[e] >> 9], 1);
    }
    __syncthreads();
    if (t < NBUCK) bcnt[t * NBLKP + blk] = lc[t];
}

__global__ __launch_bounds__(256) void scanBB_k(const int* __restrict__ bcnt, int* __restrict__ ebase,
                                                int* __restrict__ btot) {
    __shared__ int sh[256];
    int t = threadIdx.x, b = blockIdx.x;
    int c = (t < NBLKP) ? bcnt[b * NBLKP + t] : 0;
    sh[t] = c;
    __syncthreads();
    for (int off = 1; off < 256; off <<= 1) {
        int v = (t >= off) ? sh[t - off] : 0;
        __syncthreads();
        sh[t] += v;
        __syncthreads();
    }
    if (t < NBLKP) ebase[b * NBLKP + t] = sh[t] - c;  // exclusive
    if (t == 255) btot[b] = sh[255];
}

__global__ __launch_bounds__(256) void scanBT_k(const int* __restrict__ btot, int* __restrict__ bstart,
                                                int* __restrict__ offsets) {
    __shared__ int sh[256];
    int t = threadIdx.x;
    int c = (t < NBUCK) ? btot[t] : 0;
    sh[t] = c;
    __syncthreads();
    for (int off = 1; off < 256; off <<= 1) {
        int v = (t >= off) ? sh[t - off] : 0;
        __syncthreads();
        sh[t] += v;
        __syncthreads();
    }
    if (t < NBUCK) bstart[t] = sh[t] - c;
    if (t == 0) { bstart[NBUCK] = EE; offsets[NN] = EE; }
}

__global__ __launch_bounds__(256) void part_k(const int* __restrict__ src, const int* __restrict__ dst,
                                              const int* __restrict__ bstart, const int* __restrict__ ebase,
                                              int2* __restrict__ ebuf) {
    __shared__ int cur[NBUCK];
    int t = threadIdx.x, blk = blockIdx.x;
    if (t < NBUCK) cur[t] = bstart[t] + ebase[t * NBLKP + blk];
    __syncthreads();
    int e0 = blk * EPB;
    for (int i = t; i < EPB; i += 256) {
        int e = e0 + i;
        if (e < EE) {
            int s = src[e], d = dst[e];
            int p = atomicAdd(&cur[d >> 9], 1);
            ebuf[p] = make_int2(s, d);
        }
    }
}

__global__ __launch_bounds__(512) void bucket_sort_k(const int2* __restrict__ ebuf,
                                                     const int* __restrict__ bstart,
                                                     int* __restrict__ offsets,
                                                     int* __restrict__ ssrc,
                                                     int* __restrict__ sdst) {
    __shared__ int sh[512];
    __shared__ int cur[512];
    int t = threadIdx.x, b = blockIdx.x;
    int d0 = b << 9;
    int beg = bstart[b], end = bstart[b + 1];

    cur[t] = 0;
    __syncthreads();
    for (int e = beg + t; e < end; e += 512) atomicAdd(&cur[ebuf[e].y - d0], 1);
    __syncthreads();
    int c = cur[t];
    sh[t] = c;
    __syncthreads();
    for (int off = 1; off < 512; off <<= 1) {
        int v = (t >= off) ? sh[t - off] : 0;
        __syncthreads();
        sh[t] += v;
        __syncthreads();
    }
    int excl = sh[t] - c;
    if (d0 + t < NN) offsets[d0 + t] = beg + excl;
    cur[t] = beg + excl;
    __syncthreads();
    for (int e = beg + t; e < end; e += 512) {
        int2 ed = ebuf[e];
        int p = atomicAdd(&cur[ed.y - d0], 1);
        ssrc[p] = ed.x;
        sdst[p] = ed.y;
    }
}

// ---------------- W prep: transpose + fp16 round into LDS-image layout; wa = W @ a ----------------
__global__ __launch_bounds__(256) void wprep_k(const float* __restrict__ W_in,
                                               const float* __restrict__ Wl,
                                               const float* __restrict__ att_src,
                                               const float* __restrict__ att_dst,
                                               f16* __restrict__ Wt,
                                               float* __restrict__ wav) {
    int m = blockIdx.x;  // 0..4
    const float* src = (m == 0) ? W_in : (Wl + (size_t)(m - 1) * DD * DD);
    f16* dst = Wt + (size_t)m * (WCHUNKS * 8);
    for (int q = 0; q < 64; ++q) {
        int idx = q * 256 + threadIdx.x;   // 0..16383  (= k*128 + n)
        int k = idx >> 7, n = idx & 127;
        dst[n * LDA + k] = (f16)src[idx];
    }
    if (m >= 1) {
        // wa[k] = sum_n W[k][n] * a[n]  (exact f32; alpha = h . wa == (h@W) . a)
        int t = threadIdx.x;
        const float* av = (t < 128) ? (att_src + (size_t)(m - 1) * DD)
                                    : (att_dst + (size_t)(m - 1) * DD);
        int k = t & 127;
        float s = 0.f;
        for (int n = 0; n < 128; ++n) s += src[k * 128 + n] * av[n];
        wav[(size_t)(m - 1) * 256 + (t >> 7) * 128 + k] = s;
    }
}

// ---------------- fused layer-0 GEMM (R6/R9-measured form, unchanged) ----------------
__global__ __launch_bounds__(256, 2) void gemm_fused_k(const float* __restrict__ X,
                                                       const f16* __restrict__ Wt0,
                                                       const f16* __restrict__ Wt1,
                                                       const float* __restrict__ bias,
                                                       const float* __restrict__ wa_s,
                                                       const float* __restrict__ wa_d,
                                                       __half* __restrict__ Yh,
                                                       float* __restrict__ alpha_src,
                                                       float* __restrict__ alpha_dst) {
    __shared__ __align__(16) f16 sW[WCHUNKS * 8];      // 36864 B
    __shared__ __align__(16) f16 sOut[4][32][LDA];     // 34816 B
    int t = threadIdx.x;
    int w = t >> 6, lane = t & 63;
    int cl = lane & 15, qw = lane >> 4;
    int row0 = blockIdx.x * 128;

    f16x8 a[2][4];
#pragma unroll
    for (int rf = 0; rf < 2; ++rf) {
        int row = row0 + w * 32 + rf * 16 + cl;
        row = row < NN ? row : NN - 1;      // clamp (guarded at write)
        const float* p = X + (size_t)row * DD;
#pragma unroll
        for (int ks = 0; ks < 4; ++ks) {
            float4 u0 = *(const float4*)(p + ks * 32 + qw * 8);
            float4 u1 = *(const float4*)(p + ks * 32 + qw * 8 + 4);
            f16x8 v;
            v[0] = (f16)u0.x; v[1] = (f16)u0.y; v[2] = (f16)u0.z; v[3] = (f16)u0.w;
            v[4] = (f16)u1.x; v[5] = (f16)u1.y; v[6] = (f16)u1.z; v[7] = (f16)u1.w;
            a[rf][ks] = v;
        }
    }

    {
        const uint4* wsrc = (const uint4*)Wt0;
        uint4* wdst = (uint4*)sW;
#pragma unroll
        for (int it = 0; it < 9; ++it) wdst[it * 256 + t] = wsrc[it * 256 + t];
    }
    __syncthreads();

    f32x4 acc[2][8] = {};
#pragma unroll
    for (int ks = 0; ks < 4; ++ks) {
        int koff = ks * 32 + qw * 8;
#pragma unroll
        for (int nf = 0; nf < 8; ++nf) {
            f16x8 bh = *(const f16x8*)(sW + (nf * 16 + cl) * LDA + koff);
            acc[0][nf] = __builtin_amdgcn_mfma_f32_16x16x32_f16(a[0][ks], bh, acc[0][nf], 0, 0, 0);
            acc[1][nf] = __builtin_amdgcn_mfma_f32_16x16x32_f16(a[1][ks], bh, acc[1][nf], 0, 0, 0);
        }
    }

    __syncthreads();   // all waves done reading W_in image
    {
        const uint4* wsrc = (const uint4*)Wt1;
        uint4* wdst = (uint4*)sW;
#pragma unroll
        for (int it = 0; it < 9; ++it) wdst[it * 256 + t] = wsrc[it * 256 + t];
    }
    float bc[8];
#pragma unroll
    for (int nf = 0; nf < 8; ++nf) bc[nf] = bias[nf * 16 + cl];
#pragma unroll
    for (int rf = 0; rf < 2; ++rf)
#pragma unroll
        for (int i = 0; i < 4; ++i)
#pragma unroll
            for (int nf = 0; nf < 8; ++nf) {
                float v = acc[rf][nf][i] + bc[nf];
                v = v > 0.f ? v : 0.01f * v;
                sOut[w][rf * 16 + qw * 4 + i][nf * 16 + cl] = (f16)v;
            }
    __syncthreads();   // Wl_0 image staged
#pragma unroll
    for (int rf = 0; rf < 2; ++rf)
#pragma unroll
        for (int ks = 0; ks < 4; ++ks)
            a[rf][ks] = *(const f16x8*)&sOut[w][rf * 16 + cl][ks * 32 + qw * 8];
#pragma unroll
    for (int rf = 0; rf < 2; ++rf)
#pragma unroll
        for (int nf = 0; nf < 8; ++nf)
            acc[rf][nf] = (f32x4){0.f, 0.f, 0.f, 0.f};
#pragma unroll
    for (int ks = 0; ks < 4; ++ks) {
        int koff = ks * 32 + qw * 8;
#pragma unroll
        for (int nf = 0; nf < 8; ++nf) {
            f16x8 bh = *(const f16x8*)(sW + (nf * 16 + cl) * LDA + koff);
            acc[0][nf] = __builtin_amdgcn_mfma_f32_16x16x32_f16(a[0][ks], bh, acc[0][nf], 0, 0, 0);
            acc[1][nf] = __builtin_amdgcn_mfma_f32_16x16x32_f16(a[1][ks], bh, acc[1][nf], 0, 0, 0);
        }
    }

    // alpha dots from h0 fragments
#pragma unroll
    for (int rf = 0; rf < 2; ++rf) {
        float pa = 0.f, pb = 0.f;
#pragma unroll
        for (int ks = 0; ks < 4; ++ks) {
            const float* ps = wa_s + ks * 32 + qw * 8;
            const float* pd = wa_d + ks * 32 + qw * 8;
            float4 s0 = *(const float4*)ps, s1 = *(const float4*)(ps + 4);
            float4 d0 = *(const float4*)pd, d1 = *(const float4*)(pd + 4);
            float sv[8] = {s0.x, s0.y, s0.z, s0.w, s1.x, s1.y, s1.z, s1.w};
            float dv[8] = {d0.x, d0.y, d0.z, d0.w, d1.x, d1.y, d1.z, d1.w};
#pragma unroll
            for (int e = 0; e < 8; ++e) {
                float f = (float)a[rf][ks][e];
                pa = fmaf(f, sv[e], pa);
                pb = fmaf(f, dv[e], pb);
            }
        }
        pa += __shfl_xor(pa, 16); pa += __shfl_xor(pa, 32);
        pb += __shfl_xor(pb, 16); pb += __shfl_xor(pb, 32);
        if (qw == 0) {
            int row = row0 + w * 32 + rf * 16 + cl;
            if (row < NN) {
                alpha_src[row] = pa;
                alpha_dst[row] = pb;
            }
        }
    }

    // tmp store via LDS transpose
#pragma unroll
    for (int rf = 0; rf < 2; ++rf)
#pragma unroll
        for (int i = 0; i < 4; ++i)
#pragma unroll
            for (int nf = 0; nf < 8; ++nf)
                sOut[w][rf * 16 + qw * 4 + i][nf * 16 + cl] = (f16)acc[rf][nf][i];
#pragma unroll
    for (int p = 0; p < 8; ++p) {
        int rl = p * 4 + qw;
        uint4 v = *(const uint4*)&sOut[w][rl][cl * 8];
        int row = row0 + w * 32 + rl;
        if (row < NN) *(uint4*)(Yh + (size_t)row * DD + cl * 8) = v;
    }
}

// ---------------- lite GEMM: 3 blocks/CU (52.2 KB LDS), per-wave 16-row transpose chunks ----------------
__global__ __launch_bounds__(256, 3) void gemm_lite_k(const __half* __restrict__ Xh,
                                                      const f16* __restrict__ Wt0,
                                                      const float* __restrict__ wa_s,
                                                      const float* __restrict__ wa_d,
                                                      __half* __restrict__ Yh,
                                                      float* __restrict__ alpha_src,
                                                      float* __restrict__ alpha_dst) {
    __shared__ __align__(16) f16 sW[WCOPY * 8];        // 34816 B
    __shared__ __align__(16) f16 sOut[4][16][LDA];     // 17408 B
    int t = threadIdx.x;
    int w = t >> 6, lane = t & 63;
    int cl = lane & 15, qw = lane >> 4;
    int row0 = blockIdx.x * 128;

    const f16* X = (const f16*)Xh;
    f16x8 a[2][4];
#pragma unroll
    for (int rf = 0; rf < 2; ++rf) {
        int row = row0 + w * 32 + rf * 16 + cl;
        row = row < NN ? row : NN - 1;
        const f16* p = X + (size_t)row * DD;
#pragma unroll
        for (int ks = 0; ks < 4; ++ks)
            a[rf][ks] = *(const f16x8*)(p + ks * 32 + qw * 8);
    }

    {
        const uint4* wsrc = (const uint4*)Wt0;
        uint4* wdst = (uint4*)sW;
#pragma unroll
        for (int it = 0; it < 9; ++it) {
            int chunk = it * 256 + t;
            if (chunk < WCOPY) wdst[chunk] = wsrc[chunk];
        }
    }
    __syncthreads();

    f32x4 acc[2][8] = {};
#pragma unroll
    for (int ks = 0; ks < 4; ++ks) {
        int koff = ks * 32 + qw * 8;
#pragma unroll
        for (int nf = 0; nf < 8; ++nf) {
            f16x8 bh = *(const f16x8*)(sW + (nf * 16 + cl) * LDA + koff);
            acc[0][nf] = __builtin_amdgcn_mfma_f32_16x16x32_f16(a[0][ks], bh, acc[0][nf], 0, 0, 0);
            acc[1][nf] = __builtin_amdgcn_mfma_f32_16x16x32_f16(a[1][ks], bh, acc[1][nf], 0, 0, 0);
        }
    }

    // alpha dots from input-side fragments
#pragma unroll
    for (int rf = 0; rf < 2; ++rf) {
        float pa = 0.f, pb = 0.f;
#pragma unroll
        for (int ks = 0; ks < 4; ++ks) {
            const float* ps = wa_s + ks * 32 + qw * 8;
            const float* pd = wa_d + ks * 32 + qw * 8;
            float4 s0 = *(const float4*)ps, s1 = *(const float4*)(ps + 4);
            float4 d0 = *(const float4*)pd, d1 = *(const float4*)(pd + 4);
            float sv[8] = {s0.x, s0.y, s0.z, s0.w, s1.x, s1.y, s1.z, s1.w};
            float dv[8] = {d0.x, d0.y, d0.z, d0.w, d1.x, d1.y, d1.z, d1.w};
#pragma unroll
            for (int e = 0; e < 8; ++e) {
                float f = (float)a[rf][ks][e];
                pa = fmaf(f, sv[e], pa);
                pb = fmaf(f, dv[e], pb);
            }
        }
        pa += __shfl_xor(pa, 16); pa += __shfl_xor(pa, 32);
        pb += __shfl_xor(pb, 16); pb += __shfl_xor(pb, 32);
        if (qw == 0) {
            int row = row0 + w * 32 + rf * 16 + cl;
            if (row < NN) {
                alpha_src[row] = pa;
                alpha_dst[row] = pb;
            }
        }
    }

    // tmp store: per-wave 16-row transpose chunks (same-wave in-order DS, no barrier)
#pragma unroll
    for (int rf = 0; rf < 2; ++rf) {
#pragma unroll
        for (int i = 0; i < 4; ++i)
#pragma unroll
            for (int nf = 0; nf < 8; ++nf)
                sOut[w][qw * 4 + i][nf * 16 + cl] = (f16)acc[rf][nf][i];
#pragma unroll
        for (int p = 0; p < 4; ++p) {
            int rl = p * 4 + qw;
            uint4 v = *(const uint4*)&sOut[w][rl][cl * 8];
            int row = row0 + w * 32 + rf * 16 + rl;
            if (row < NN) *(uint4*)(Yh + (size_t)row * DD + cl * 8) = v;
        }
    }
}

// ---------------- per-edge packed (src, exp-weight) records + 16-record pad ----------------
__global__ __launch_bounds__(256) void edgew_k(const int* __restrict__ ssrc,
                                               const int* __restrict__ sdst,
                                               const float* __restrict__ alpha_src,
                                               const float* __restrict__ alpha_dst,
                                               int2* __restrict__ epk) {
    int j = blockIdx.x * 256 + threadIdx.x;
    if (j < EE) {
        int s = ssrc[j];
        float e = alpha_src[s] + alpha_dst[sdst[j]];
        e = e > 0.f ? e : 0.2f * e;
        epk[j] = make_int2(s, __float_as_int(__expf(e)));
    } else if (j < EE + 16) {
        epk[j] = make_int2(0, 0);   // pad: row 0, weight 0 (masked anyway)
    }
}

// ---------------- Per-dst aggregation + softmax-normalize + bias + LN + leaky ----------------
// (R8-measured form: 65.3 us. epk scalar loads + SRSRC gathers with SGPR soffset.)
template <int HOUT>
__global__ __launch_bounds__(256) void agg_k(const __half* __restrict__ tmp,
                                             const int2* __restrict__ epk,
                                             const int* __restrict__ offsets,
                                             const float* __restrict__ bias,
                                             const float* __restrict__ gamma,
                                             const float* __restrict__ beta,
                                             void* __restrict__ outv) {
    int wid = (blockIdx.x * 256 + threadIdx.x) >> 6;
    wid = __builtin_amdgcn_readfirstlane(wid);
    int lane = threadIdx.x & 63;
    int beg = __builtin_amdgcn_readfirstlane(offsets[wid]);
    int end = __builtin_amdgcn_readfirstlane(offsets[wid + 1]);

    int32x4 rsrc;
    {
        unsigned long long b = (unsigned long long)(uintptr_t)tmp;
        rsrc.x = (int)(b & 0xffffffffull);
        rsrc.y = (int)(b >> 32);
        rsrc.z = NN * 256;          // num_records in bytes
        rsrc.w = 0x00020000;        // raw dword access
    }
    int voff = lane << 2;

    float ax0 = 0.f, ay0 = 0.f, ax1 = 0.f, ay1 = 0.f, dsum = 0.f;

    for (int j = (beg & ~1); j < end; j += 16) {
        int4 q[8];
#pragma unroll
        for (int k = 0; k < 8; ++k) q[k] = *(const int4*)(epk + j + 2 * k);
        float g[16];
#pragma unroll
        for (int k = 0; k < 8; ++k) {
            g[2 * k]     = llvm_amdgcn_raw_buffer_load_fp32(rsrc, voff, q[k].x << 8, 0);
            g[2 * k + 1] = llvm_amdgcn_raw_buffer_load_fp32(rsrc, voff, q[k].z << 8, 0);
        }
#pragma unroll
        for (int k = 0; k < 8; ++k) {
            int e0 = j + 2 * k, e1 = e0 + 1;
            bool v0 = (k == 0) ? (e0 >= beg && e0 < end) : (e0 < end);
            bool v1 = (e1 < end);
            float w0 = v0 ? __int_as_float(q[k].y) : 0.f;
            float w1 = v1 ? __int_as_float(q[k].w) : 0.f;
            union { float f; __half2 h; } u0, u1;
            u0.f = g[2 * k]; u1.f = g[2 * k + 1];
            dsum += w0 + w1;
            ax0 = fmaf(w0, __half2float(u0.h.x), ax0);
            ay0 = fmaf(w0, __half2float(u0.h.y), ay0);
            ax1 = fmaf(w1, __half2float(u1.h.x), ax1);
            ay1 = fmaf(w1, __half2float(u1.h.y), ay1);
        }
    }

    // dsum is lane-uniform: no cross-lane reduction needed
    float inv = 1.0f / (dsum + 1e-16f);

    float ax = (ax0 + ax1) * inv + bias[2 * lane];
    float ay = (ay0 + ay1) * inv + bias[2 * lane + 1];

    float s1 = ax + ay;
#pragma unroll
    for (int off = 32; off >= 1; off >>= 1) s1 += __shfl_xor(s1, off);
    float mu = s1 * (1.0f / 128.0f);
    float dx = ax - mu, dy = ay - mu;
    float s2 = dx * dx + dy * dy;
#pragma unroll
    for (int off = 32; off >= 1; off >>= 1) s2 += __shfl_xor(s2, off);
    float rstd = rsqrtf(s2 * (1.0f / 128.0f) + 1e-5f);

    float yx = dx * rstd * gamma[2 * lane] + beta[2 * lane];
    float yy = dy * rstd * gamma[2 * lane + 1] + beta[2 * lane + 1];
    yx = yx > 0.f ? yx : 0.01f * yx;
    yy = yy > 0.f ? yy : 0.01f * yy;
    if (HOUT) {
        ((__half2*)outv)[(size_t)wid * 64 + lane] = __floats2half2_rn(yx, yy);
    } else {
        ((float2*)outv)[(size_t)wid * 64 + lane] = make_float2(yx, yy);
    }
}

extern "C" void kernel_launch(void* const* d_in, const int* in_sizes, int n_in,
                              void* d_out, int out_size, void* d_ws, size_t ws_size,
                              hipStream_t stream) {
    const float* x       = (const float*)d_in[0];
    const int*   ei      = (const int*)d_in[1];
    const float* W_in    = (const float*)d_in[2];
    const float* b_in    = (const float*)d_in[3];
    const float* Wl      = (const float*)d_in[4];
    const float* att_src = (const float*)d_in[5];
    const float* att_dst = (const float*)d_in[6];
    const float* bias_l  = (const float*)d_in[7];
    const float* gamma   = (const float*)d_in[8];
    const float* beta    = (const float*)d_in[9];
    float* out = (float*)d_out;

    char* ws = (char*)d_ws;
    __half* tmp      = (__half*)ws; ws += (size_t)NN * DD * 2;   // 25.6 MB
    float* alpha_src = (float*)ws;  ws += (size_t)NN * 4;
    float* alpha_dst = (float*)ws;  ws += (size_t)NN * 4;
    int*   offsets   = (int*)ws;    ws += (size_t)(NN + 4) * 4;
    int*   ssrc      = (int*)ws;    ws += (size_t)EE * 4;        // 6.4 MB
    int*   sdst      = (int*)ws;    ws += (size_t)EE * 4;        // 6.4 MB
    int2*  ebuf      = (int2*)ws;   ws += (size_t)(EE + 16) * 8; // 12.8 MB (dead after CSR build)
    int*   bcnt      = (int*)ws;    ws += (size_t)NBUCK * NBLKP * 4;
    int*   ebase     = (int*)ws;    ws += (size_t)NBUCK * NBLKP * 4;
    int*   btot      = (int*)ws;    ws += (size_t)(NBUCK + 4) * 4;
    int*   bstart    = (int*)ws;    ws += (size_t)(NBUCK + 4) * 4;
    f16*   Wt        = (f16*)ws;    ws += (size_t)5 * WCHUNKS * 16;  // 184 KB
    float* wav       = (float*)ws;  ws += (size_t)4 * 256 * 4;       // 4 KB (wa vectors)
    int2* epk = ebuf;               // aliases ebuf: written only after bucket_sort_k

    // fp16 hidden-state buffer lives in the (not-yet-needed) d_out allocation:
    // layers 0..2 store h as fp16 in the first 25.6 MB; the final agg_k fully
    // overwrites d_out with fp32 output.
    __half* hbuf = (__half*)d_out;

    const int* esrc = ei;
    const int* edst = ei + EE;

    // bucketed CSR build (edges constant within a launch)
    part_hist_k<<<NBLKP, 256, 0, stream>>>(edst, bcnt);
    scanBB_k<<<NBUCK, 256, 0, stream>>>(bcnt, ebase, btot);
    scanBT_k<<<1, 256, 0, stream>>>(btot, bstart, offsets);
    part_k<<<NBLKP, 256, 0, stream>>>(esrc, edst, bstart, ebase, ebuf);
    bucket_sort_k<<<NBUCK, 512, 0, stream>>>(ebuf, bstart, offsets, ssrc, sdst);
    wprep_k<<<5, 256, 0, stream>>>(W_in, Wl, att_src, att_dst, Wt, wav);

    const int gg = (NN + 127) / 128;          // 782
    const int eg = (EE + 16 + 255) / 256;     // 6251 (covers pad records)

    // layer 0: fused  tmp = (leaky(x@W_in + b)) @ Wl_0  + alpha_0  (h0 never hits HBM)
    gemm_fused_k<<<gg, 256, 0, stream>>>(x, Wt, Wt + (size_t)1 * (WCHUNKS * 8), b_in,
                                         wav, wav + 128, tmp, alpha_src, alpha_dst);
    edgew_k<<<eg, 256, 0, stream>>>(ssrc, sdst, alpha_src, alpha_dst, epk);
    agg_k<1><<<NN / 4, 256, 0, stream>>>(tmp, epk, offsets, bias_l, gamma, beta, (void*)hbuf);

    for (int i = 1; i < 4; i++) {
        gemm_lite_k<<<gg, 256, 0, stream>>>(hbuf, Wt + (size_t)(i + 1) * (WCHUNKS * 8),
                                            wav + (size_t)i * 256, wav + (size_t)i * 256 + 128,
                                            tmp, alpha_src, alpha_dst);
        edgew_k<<<eg, 256, 0, stream>>>(ssrc, sdst, alpha_src, alpha_dst, epk);
        if (i < 3) {
            agg_k<1><<<NN / 4, 256, 0, stream>>>(tmp, epk, offsets,
                                                 bias_l + (size_t)i * DD, gamma + (size_t)i * DD,
                                                 beta + (size_t)i * DD, (void*)hbuf);
        } else {
            agg_k<0><<<NN / 4, 256, 0, stream>>>(tmp, epk, offsets,
                                                 bias_l + (size_t)i * DD, gamma + (size_t)i * DD,
                                                 beta + (size_t)i * DD, (void*)out);
        }
    }
}